// Round 17
// baseline (404.495 us; speedup 1.0000x reference)
//
#include <hip/hip_runtime.h>

typedef _Float16 f16;
typedef _Float16 f16x8 __attribute__((ext_vector_type(8)));
typedef _Float16 f16x4 __attribute__((ext_vector_type(4)));
typedef float    f32x4 __attribute__((ext_vector_type(4)));
typedef float    f32x8 __attribute__((ext_vector_type(8)));

#define H  128
#define G3 384
#define AH 36
#define PADW 136   // padded LDS row: 136 f16 = 272B

// v_rcp_f32 (~1 ulp) — proven R10.
__device__ __forceinline__ float sigmoidf_(float x){
  return __builtin_amdgcn_rcpf(1.f + __expf(-x));
}
__device__ __forceinline__ float tanhf_(float x){
  return fmaf(2.f, __builtin_amdgcn_rcpf(1.f + __expf(-2.f*x)), -1.f);
}

// LDS-only barrier: global prefetch loads stay in flight across it.
__device__ __forceinline__ void lds_sync(){
  asm volatile("s_waitcnt lgkmcnt(0)" ::: "memory");
  __builtin_amdgcn_s_barrier();
  asm volatile("" ::: "memory");
}

// ---------------- prep: weights fp32 -> fp16, lengths ----------------
__global__ void prep_weights(const float* __restrict__ a, const float* __restrict__ b,
                             const float* __restrict__ c, const float* __restrict__ d,
                             f16* __restrict__ dst)
{
  int i = blockIdx.x * 256 + threadIdx.x;
  if (i >= 4 * G3 * H) return;
  int m = i / (G3 * H), j = i % (G3 * H);
  const float* s = (m == 0) ? a : (m == 1) ? b : (m == 2) ? c : d;
  dst[i] = (f16)s[j];
}

__global__ void prep_len(const int* __restrict__ mask, int* __restrict__ len, int T, int B)
{
  int b = blockIdx.x * 256 + threadIdx.x;
  if (b >= B) return;
  int s = 0;
  for (int t = 0; t < T; ++t) s += (mask[(size_t)b * T + t] > 0);
  len[b] = s;
}

// ---------------- fused GRU / AUGRU scan (v13: 4 waves, 32 cols/wave, 512-VGPR budget) ----------------
// 256 thr = 4 waves = 1 wave/SIMD. Wave w owns gate cols [32w,32w+32) for all
// 3 gates (48 weight frags = 192 VGPR; legal under waves_per_eu(1,1) -> 512 cap).
// Halves the CU's per-step ds_read_b128 count (was 8x-redundant across 8 waves).
template<bool AUG>
__global__ __launch_bounds__(256)
__attribute__((amdgpu_waves_per_eu(1, 1)))
void scan_kernel(const float* __restrict__ xf32,  // GRU input  [B,T,H] f32
                 const f16*   __restrict__ xf16,  // AUGRU input (hist) [B,T,H] f16
                 const f16*   __restrict__ Wih,   // [3H][H] f16
                 const f16*   __restrict__ Whh,   // [3H][H] f16
                 const float* __restrict__ bih,
                 const float* __restrict__ bhh,
                 const float* __restrict__ att,   // [B,T] (AUG)
                 const int*   __restrict__ len,   // [B]   (AUG)
                 f16*         __restrict__ histo, // [B,T,H] f16 (GRU)
                 float*       __restrict__ outp,  // [B,H]       (AUG)
                 int T)
{
  __shared__ f16  xs[2][16 * PADW];
  __shared__ f16  hs[2][16 * PADW];

  const int tid = threadIdx.x;
  const int w   = tid >> 6;          // 0..3
  const int l   = tid & 63;
  const int l16 = l & 15;
  const int lhi = l >> 4;
  const int b0  = blockIdx.x * 16;
  const int colb = w * 32;           // 32 cols per wave
  const int c4a  = colb + lhi * 4;   // subtile 0 cols
  // subtile 1 cols = c4a + 16
  const int srow = tid >> 4;         // 0..15 (staging row, 256 thr)
  const int scol = (tid & 15) * 8;   // 8 f16 per thread

  // Weight fragments: 3 gates x 2 col-subtiles x 4 q = 48 f16x8 (192 VGPR), pinned.
  f16x8 wih[3][2][4], whh[3][2][4];
  #pragma unroll
  for (int g = 0; g < 3; ++g)
    #pragma unroll
    for (int c = 0; c < 2; ++c)
      #pragma unroll
      for (int q = 0; q < 4; ++q) {
        int off = (g * H + colb + 16 * c + l16) * H + q * 32 + lhi * 8;
        wih[g][c][q] = *(const f16x8*)(Wih + off);
        whh[g][c][q] = *(const f16x8*)(Whh + off);
      }
  #pragma unroll
  for (int g = 0; g < 3; ++g)
    #pragma unroll
    for (int c = 0; c < 2; ++c)
      #pragma unroll
      for (int q = 0; q < 4; ++q)
        asm volatile("" : "+v"(wih[g][c][q]), "+v"(whh[g][c][q]));

  // bias C-inits for both subtiles
  f32x4 bR0  = *(const f32x4*)(bih + c4a);
  { f32x4 t2 = *(const f32x4*)(bhh + c4a);           bR0 += t2; }
  f32x4 bR1  = *(const f32x4*)(bih + c4a + 16);
  { f32x4 t2 = *(const f32x4*)(bhh + c4a + 16);      bR1 += t2; }
  f32x4 bZ0  = *(const f32x4*)(bih + H + c4a);
  { f32x4 t2 = *(const f32x4*)(bhh + H + c4a);       bZ0 += t2; }
  f32x4 bZ1  = *(const f32x4*)(bih + H + c4a + 16);
  { f32x4 t2 = *(const f32x4*)(bhh + H + c4a + 16);  bZ1 += t2; }
  const f32x4 bXn0 = *(const f32x4*)(bih + 2*H + c4a);
  const f32x4 bXn1 = *(const f32x4*)(bih + 2*H + c4a + 16);
  const f32x4 bHn0 = *(const f32x4*)(bhh + 2*H + c4a);
  const f32x4 bHn1 = *(const f32x4*)(bhh + 2*H + c4a + 16);

  float hold0[4] = {0.f,0.f,0.f,0.f}, hold1[4] = {0.f,0.f,0.f,0.f};
  int len_l = 0;
  if (AUG) len_l = len[b0 + l16];

  // hoisted LDS pointers
  const f16* xrd0 = &xs[0][l16 * PADW + lhi * 8];
  const f16* xrd1 = &xs[1][l16 * PADW + lhi * 8];
  const f16* hrd0 = &hs[0][l16 * PADW + lhi * 8];
  const f16* hrd1 = &hs[1][l16 * PADW + lhi * 8];
  f16* hwr0 = &hs[0][l16 * PADW + c4a];
  f16* hwr1 = &hs[1][l16 * PADW + c4a];
  f16* xst0 = &xs[0][srow * PADW + scol];
  f16* xst1 = &xs[1][srow * PADW + scol];

  // running global pointers (staging: 8 f16 per thread)
  const float* pxA32 = xf32 ? (xf32 + ((size_t)(b0 + srow) * T) * H + scol) : nullptr;
  const f16*   pxA16 = xf16 ? (xf16 + ((size_t)(b0 + srow) * T) * H + scol) : nullptr;
  const float* attB  = AUG ? (att + (size_t)(b0 + l16) * T) : nullptr;
  f16*         histp = (!AUG && histo) ? (histo + ((size_t)(b0 + l16) * T) * H + c4a) : nullptr;
  float*       outpp = AUG ? (outp + (size_t)(b0 + l16) * H + c4a) : nullptr;

  // prologue: zero h buf 0, stage x_0, prefetch x_1
  {
    f16x8 z8 = {};
    *(f16x8*)(&hs[0][srow * PADW + scol]) = z8;
    if (AUG) {
      *(f16x8*)xst0 = *(const f16x8*)(pxA16);
    } else {
      f32x8 v = *(const f32x8*)(pxA32);
      f16x8 h8 = {(f16)v[0],(f16)v[1],(f16)v[2],(f16)v[3],(f16)v[4],(f16)v[5],(f16)v[6],(f16)v[7]};
      *(f16x8*)xst0 = h8;
    }
  }
  f32x8 Pa32 = {}, Pb32 = {};
  f16x8 Pa16 = {}, Pb16 = {};
  float Aa = 0.f, Ab = 0.f;
  if (AUG) {
    if (T > 1) Pa16 = *(const f16x8*)(pxA16 + H);
    Aa = attB[0];
    if (T > 1) Ab = attB[1];
  } else {
    if (T > 1) Pa32 = *(const f32x8*)(pxA32 + H);
  }
  const float* pxE32 = pxA32 ? pxA32 + 2 * H : nullptr;
  const float* pxO32 = pxA32 ? pxA32 + 3 * H : nullptr;
  const f16*   pxE16 = pxA16 ? pxA16 + 2 * H : nullptr;
  const f16*   pxO16 = pxA16 ? pxA16 + 3 * H : nullptr;
  lds_sync();

// Macro-internal names suffixed (R3 lesson). R10's interleave, 2 col-subtiles.
#define STEP(targ_, XRD, HRD, HWRN, XSTN, PW32, PL32, PW16, PL16, AW, PXP32, PXP16) \
  {                                                                            \
    const int t5_  = (targ_);                                                  \
    float at_ = 0.f;                                                           \
    if (AUG) at_ = AW;                                                         \
    if (t5_ + 2 < T) {                                                         \
      if (AUG) {                                                               \
        PL16 = *(const f16x8*)(PXP16);  PXP16 += 2 * H;                        \
        AW = attB[t5_ + 2];                                                    \
      } else {                                                                 \
        PL32 = *(const f32x8*)(PXP32);  PXP32 += 2 * H;                        \
      }                                                                        \
    }                                                                          \
    f16x8 xb[4], hb[4];                                                        \
    _Pragma("unroll")                                                          \
    for (int q = 0; q < 4; ++q) {                                              \
      xb[q] = *(const f16x8*)(XRD + q * 32);                                   \
      hb[q] = *(const f16x8*)(HRD + q * 32);                                   \
    }                                                                          \
    f32x4 aR0 = bR0, aR1 = bR1, aZ0 = bZ0, aZ1 = bZ1;                          \
    f32x4 aXn0 = bXn0, aXn1 = bXn1, aHn0 = bHn0, aHn1 = bHn1;                  \
    _Pragma("unroll")                                                          \
    for (int q = 0; q < 4; ++q) {                                              \
      aR0  = __builtin_amdgcn_mfma_f32_16x16x32_f16(wih[0][0][q], xb[q], aR0, 0,0,0); \
      aR1  = __builtin_amdgcn_mfma_f32_16x16x32_f16(wih[0][1][q], xb[q], aR1, 0,0,0); \
      aZ0  = __builtin_amdgcn_mfma_f32_16x16x32_f16(wih[1][0][q], xb[q], aZ0, 0,0,0); \
      aZ1  = __builtin_amdgcn_mfma_f32_16x16x32_f16(wih[1][1][q], xb[q], aZ1, 0,0,0); \
      aXn0 = __builtin_amdgcn_mfma_f32_16x16x32_f16(wih[2][0][q], xb[q], aXn0,0,0,0); \
      aXn1 = __builtin_amdgcn_mfma_f32_16x16x32_f16(wih[2][1][q], xb[q], aXn1,0,0,0); \
      aHn0 = __builtin_amdgcn_mfma_f32_16x16x32_f16(whh[2][0][q], hb[q], aHn0,0,0,0); \
      aHn1 = __builtin_amdgcn_mfma_f32_16x16x32_f16(whh[2][1][q], hb[q], aHn1,0,0,0); \
    }                                                                          \
    _Pragma("unroll")                                                          \
    for (int q = 0; q < 4; ++q) {                                              \
      aR0 = __builtin_amdgcn_mfma_f32_16x16x32_f16(whh[0][0][q], hb[q], aR0, 0,0,0);  \
      aR1 = __builtin_amdgcn_mfma_f32_16x16x32_f16(whh[0][1][q], hb[q], aR1, 0,0,0);  \
      aZ0 = __builtin_amdgcn_mfma_f32_16x16x32_f16(whh[1][0][q], hb[q], aZ0, 0,0,0);  \
      aZ1 = __builtin_amdgcn_mfma_f32_16x16x32_f16(whh[1][1][q], hb[q], aZ1, 0,0,0);  \
    }                                                                          \
    float hn0_[4], hn1_[4];                                                    \
    _Pragma("unroll")                                                          \
    for (int i = 0; i < 4; ++i) {                                              \
      float r = sigmoidf_(aR0[i]);                                             \
      float z = sigmoidf_(aZ0[i]);                                             \
      float n = tanhf_(aXn0[i] + r * aHn0[i]);                                 \
      float h;                                                                 \
      if (AUG) { float u = z * at_; h = hold0[i] + u * (n - hold0[i]); }       \
      else     { h = n + z * (hold0[i] - n); }                                 \
      hold0[i] = h; hn0_[i] = h;                                               \
    }                                                                          \
    _Pragma("unroll")                                                          \
    for (int i = 0; i < 4; ++i) {                                              \
      float r = sigmoidf_(aR1[i]);                                             \
      float z = sigmoidf_(aZ1[i]);                                             \
      float n = tanhf_(aXn1[i] + r * aHn1[i]);                                 \
      float h;                                                                 \
      if (AUG) { float u = z * at_; h = hold1[i] + u * (n - hold1[i]); }       \
      else     { h = n + z * (hold1[i] - n); }                                 \
      hold1[i] = h; hn1_[i] = h;                                               \
    }                                                                          \
    f16x4 hv0 = {(f16)hn0_[0], (f16)hn0_[1], (f16)hn0_[2], (f16)hn0_[3]};      \
    f16x4 hv1 = {(f16)hn1_[0], (f16)hn1_[1], (f16)hn1_[2], (f16)hn1_[3]};      \
    *(f16x4*)(HWRN)      = hv0;                                                \
    *(f16x4*)(HWRN + 16) = hv1;                                                \
    if (!AUG) {                                                                \
      *(f16x4*)(histp)      = hv0;                                             \
      *(f16x4*)(histp + 16) = hv1;                                             \
      histp += H;                                                              \
    } else {                                                                   \
      if (t5_ == len_l - 1) {                                                  \
        f32x4 o0 = {hn0_[0], hn0_[1], hn0_[2], hn0_[3]};                       \
        f32x4 o1 = {hn1_[0], hn1_[1], hn1_[2], hn1_[3]};                       \
        *(f32x4*)(outpp)      = o0;                                            \
        *(f32x4*)(outpp + 16) = o1;                                            \
      }                                                                        \
    }                                                                          \
    if (t5_ + 1 < T) {                                                         \
      if (AUG) {                                                               \
        *(f16x8*)(XSTN) = PW16;                                                \
      } else {                                                                 \
        f16x8 s8 = {(f16)PW32[0],(f16)PW32[1],(f16)PW32[2],(f16)PW32[3],       \
                    (f16)PW32[4],(f16)PW32[5],(f16)PW32[6],(f16)PW32[7]};      \
        *(f16x8*)(XSTN) = s8;                                                  \
      }                                                                        \
    }                                                                          \
    lds_sync();                                                                \
  }

  for (int t = 0; t < T; t += 2) {
    STEP(t,     xrd0, hrd0, hwr1, xst1, Pa32, Pb32, Pa16, Pb16, Aa, pxE32, pxE16)
    STEP(t + 1, xrd1, hrd1, hwr0, xst0, Pb32, Pa32, Pb16, Pa16, Ab, pxO32, pxO16)
  }
#undef STEP
}

// ---------------- DIN attention (MFMA version; rcp sigmoid — R10) ----------------
__global__ __launch_bounds__(256)
void attn_kernel(const float* __restrict__ query,
                 const f16*   __restrict__ hist,
                 const int*   __restrict__ mask,
                 const float* __restrict__ W1, const float* __restrict__ b1,
                 const float* __restrict__ W2, const float* __restrict__ b2,
                 float* __restrict__ attv, int T)
{
  __shared__ float qs[H];
  __shared__ f16   WqH[48 * PADW];
  __shared__ float qcp[48], w2p[48];
  __shared__ float logitsS[224];
  __shared__ float red[256];

  const int tid = threadIdx.x, b = blockIdx.x;
  const int w = tid >> 6, l = tid & 63, l16 = l & 15, lhi = l >> 4;

  if (tid < H) qs[tid] = query[b * H + tid];
  if (tid < 48) w2p[tid] = (tid < AH) ? W2[tid] : 0.f;
  __syncthreads();

  for (int i = tid; i < 48 * H; i += 256) {
    int u = i >> 7, k = i & (H - 1);
    float v = 0.f;
    if (u < AH) {
      const float* r = W1 + u * 4 * H;
      v = r[H + k] - r[2*H + k] + qs[k] * r[3*H + k];
    }
    WqH[u * PADW + k] = (f16)v;
  }
  if (tid < 48) {
    float s = 0.f;
    if (tid < AH) {
      const float* r = W1 + tid * 4 * H;
      s = b1[tid];
      for (int k = 0; k < H; ++k) s += qs[k] * (r[k] + r[2*H + k]);
    }
    qcp[tid] = s;
  }
  __syncthreads();

  const f32x4 qcv0 = *(const f32x4*)&qcp[lhi*4];
  const f32x4 qcv1 = *(const f32x4*)&qcp[16 + lhi*4];
  const f32x4 qcv2 = *(const f32x4*)&qcp[32 + lhi*4];
  const f32x4 w2v0 = *(const f32x4*)&w2p[lhi*4];
  const f32x4 w2v1 = *(const f32x4*)&w2p[16 + lhi*4];
  const f32x4 w2v2 = *(const f32x4*)&w2p[32 + lhi*4];

  const int NMT = (T + 15) >> 4;
  for (int mt = w; mt < NMT; mt += 4) {
    const int t0 = mt * 16;
    f16x8 hbf[4];
    #pragma unroll
    for (int q = 0; q < 4; ++q)
      hbf[q] = *(const f16x8*)(hist + ((size_t)b*T + t0 + l16)*H + q*32 + lhi*8);
    f32x4 d0 = {0,0,0,0}, d1 = {0,0,0,0}, d2 = {0,0,0,0};
    #pragma unroll
    for (int q = 0; q < 4; ++q) {
      f16x8 wq0 = *(const f16x8*)(&WqH[ l16       * PADW + q*32 + lhi*8]);
      f16x8 wq1 = *(const f16x8*)(&WqH[(16 + l16) * PADW + q*32 + lhi*8]);
      f16x8 wq2 = *(const f16x8*)(&WqH[(32 + l16) * PADW + q*32 + lhi*8]);
      d0 = __builtin_amdgcn_mfma_f32_16x16x32_f16(wq0, hbf[q], d0, 0,0,0);
      d1 = __builtin_amdgcn_mfma_f32_16x16x32_f16(wq1, hbf[q], d1, 0,0,0);
      d2 = __builtin_amdgcn_mfma_f32_16x16x32_f16(wq2, hbf[q], d2, 0,0,0);
    }
    float p = 0.f;
    #pragma unroll
    for (int i = 0; i < 4; ++i) {
      p += w2v0[i] * sigmoidf_(d0[i] + qcv0[i]);
      p += w2v1[i] * sigmoidf_(d1[i] + qcv1[i]);
      p += w2v2[i] * sigmoidf_(d2[i] + qcv2[i]);
    }
    p += __shfl_xor(p, 16, 64);
    p += __shfl_xor(p, 32, 64);
    if (lhi == 0) logitsS[t0 + l16] = p;
  }
  __syncthreads();

  const int t = tid;
  float logit = -1e30f; int mk = 0;
  if (t < T) {
    mk = mask[(size_t)b*T + t];
    logit = (mk > 0) ? (logitsS[t] + b2[0]) : -1e30f;
  }
  red[tid] = logit; __syncthreads();
  for (int s = 128; s > 0; s >>= 1) { if (tid < s) red[tid] = fmaxf(red[tid], red[tid+s]); __syncthreads(); }
  float mx = red[0]; __syncthreads();
  float ev = (t < T && mk > 0) ? __expf(logit - mx) : 0.f;
  red[tid] = ev; __syncthreads();
  for (int s = 128; s > 0; s >>= 1) { if (tid < s) red[tid] += red[tid+s]; __syncthreads(); }
  float sm = red[0];
  if (t < T) attv[(size_t)b*T + t] = ev * __builtin_amdgcn_rcpf(sm);
}

// ---------------- host ----------------
extern "C" void kernel_launch(void* const* d_in, const int* in_sizes, int n_in,
                              void* d_out, int out_size, void* d_ws, size_t ws_size,
                              hipStream_t stream)
{
  const float* query = (const float*)d_in[0];
  const float* ub    = (const float*)d_in[1];
  const int*   mask  = (const int*)d_in[2];
  const float* gWih  = (const float*)d_in[3];
  const float* gWhh  = (const float*)d_in[4];
  const float* gbih  = (const float*)d_in[5];
  const float* gbhh  = (const float*)d_in[6];
  const float* aW1   = (const float*)d_in[7];
  const float* ab1   = (const float*)d_in[8];
  const float* aW2   = (const float*)d_in[9];
  const float* ab2   = (const float*)d_in[10];
  const float* uWih  = (const float*)d_in[11];
  const float* uWhh  = (const float*)d_in[12];
  const float* ubih  = (const float*)d_in[13];
  const float* ubhh  = (const float*)d_in[14];

  const int B = in_sizes[0] / H;            // 1024
  const int T = in_sizes[1] / in_sizes[0];  // 200

  // workspace layout
  char*  ws   = (char*)d_ws;
  f16*   wf   = (f16*)ws;                                   // 393216 B
  int*   lenp = (int*)(ws + 393216);                        // 4096 B
  float* attb = (float*)(ws + 397312);                      // B*T*4
  f16*   hist = (f16*)(ws + 397312 + (size_t)B * 200 * 4);  // B*T*H f16

  prep_weights<<<(4 * G3 * H + 255) / 256, 256, 0, stream>>>(gWih, gWhh, uWih, uWhh, wf);
  prep_len<<<(B + 255) / 256, 256, 0, stream>>>(mask, lenp, T, B);

  scan_kernel<false><<<B / 16, 256, 0, stream>>>(
      ub, (const f16*)nullptr, wf, wf + G3 * H, gbih, gbhh,
      (const float*)nullptr, (const int*)nullptr, hist, (float*)nullptr, T);

  attn_kernel<<<B, 256, 0, stream>>>(query, hist, mask, aW1, ab1, aW2, ab2, attb, T);

  scan_kernel<true><<<B / 16, 256, 0, stream>>>(
      (const float*)nullptr, hist, wf + 2 * G3 * H, wf + 3 * G3 * H, ubih, ubhh,
      attb, lenp, (f16*)nullptr, (float*)d_out, T);
}

// Round 18
// 367.324 us; speedup vs baseline: 1.1012x; 1.1012x over previous
//
#include <hip/hip_runtime.h>

typedef _Float16 f16;
typedef _Float16 f16x8 __attribute__((ext_vector_type(8)));
typedef _Float16 f16x4 __attribute__((ext_vector_type(4)));
typedef float    f32x4 __attribute__((ext_vector_type(4)));

#define H  128
#define G3 384
#define AH 36
#define PADW 136   // padded LDS row: 136 f16 = 272B

// v_rcp_f32 (~1 ulp) instead of IEEE division (proven R10: -100µs total)
__device__ __forceinline__ float sigmoidf_(float x){
  return __builtin_amdgcn_rcpf(1.f + __expf(-x));
}
__device__ __forceinline__ float tanhf_(float x){
  return fmaf(2.f, __builtin_amdgcn_rcpf(1.f + __expf(-2.f*x)), -1.f);
}

// LDS-only barrier: drain LDS ops, then s_barrier. Global prefetch loads
// stay in flight across it.
__device__ __forceinline__ void lds_sync(){
  asm volatile("s_waitcnt lgkmcnt(0)" ::: "memory");
  __builtin_amdgcn_s_barrier();
  asm volatile("" ::: "memory");
}

// ---------------- prep: weights fp32 -> fp16, lengths ----------------
__global__ void prep_weights(const float* __restrict__ a, const float* __restrict__ b,
                             const float* __restrict__ c, const float* __restrict__ d,
                             f16* __restrict__ dst)
{
  int i = blockIdx.x * 256 + threadIdx.x;
  if (i >= 4 * G3 * H) return;
  int m = i / (G3 * H), j = i % (G3 * H);
  const float* s = (m == 0) ? a : (m == 1) ? b : (m == 2) ? c : d;
  dst[i] = (f16)s[j];
}

__global__ void prep_len(const int* __restrict__ mask, int* __restrict__ len, int T, int B)
{
  int b = blockIdx.x * 256 + threadIdx.x;
  if (b >= B) return;
  int s = 0;
  for (int t = 0; t < T; ++t) s += (mask[(size_t)b * T + t] > 0);
  len[b] = s;
}

// ---------------- fused GRU / AUGRU scan (R10 optimum) ----------------
template<bool AUG>
__global__ __launch_bounds__(512)
__attribute__((amdgpu_waves_per_eu(2, 2)))
void scan_kernel(const float* __restrict__ xf32,  // GRU input  [B,T,H] f32
                 const f16*   __restrict__ xf16,  // AUGRU input (hist) [B,T,H] f16
                 const f16*   __restrict__ Wih,   // [3H][H] f16
                 const f16*   __restrict__ Whh,   // [3H][H] f16
                 const float* __restrict__ bih,
                 const float* __restrict__ bhh,
                 const float* __restrict__ att,   // [B,T] (AUG)
                 const int*   __restrict__ len,   // [B]   (AUG)
                 f16*         __restrict__ histo, // [B,T,H] f16 (GRU)
                 float*       __restrict__ outp,  // [B,H]       (AUG)
                 int T)
{
  __shared__ f16  xs[2][16 * PADW];
  __shared__ f16  hs[2][16 * PADW];

  const int tid = threadIdx.x;
  const int w   = tid >> 6;
  const int l   = tid & 63;
  const int l16 = l & 15;
  const int lhi = l >> 4;
  const int b0  = blockIdx.x * 16;
  const int colb = w * 16;
  const int c4   = colb + lhi * 4;
  const int srow = tid >> 5, cc = tid & 31;

  // Weight fragments (24 x f16x8 = 96 regs), pinned.
  f16x8 wih[3][4], whh[3][4];
  #pragma unroll
  for (int g = 0; g < 3; ++g)
    #pragma unroll
    for (int q = 0; q < 4; ++q) {
      int off = (g * H + colb + l16) * H + q * 32 + lhi * 8;
      wih[g][q] = *(const f16x8*)(Wih + off);
      whh[g][q] = *(const f16x8*)(Whh + off);
    }
  #pragma unroll
  for (int g = 0; g < 3; ++g)
    #pragma unroll
    for (int q = 0; q < 4; ++q)
      asm volatile("" : "+v"(wih[g][q]), "+v"(whh[g][q]));

  // bias vectors for the lane's 4 cols (accumulator init)
  f32x4 bR  = *(const f32x4*)(bih + c4);
  { f32x4 t2 = *(const f32x4*)(bhh + c4);      bR  += t2; }
  f32x4 bZ  = *(const f32x4*)(bih + H + c4);
  { f32x4 t2 = *(const f32x4*)(bhh + H + c4);  bZ  += t2; }
  f32x4 bXn = *(const f32x4*)(bih + 2*H + c4);
  f32x4 bHn = *(const f32x4*)(bhh + 2*H + c4);

  float hold[4] = {0.f, 0.f, 0.f, 0.f};
  int len_l = 0;
  if (AUG) len_l = len[b0 + l16];

  // hoisted LDS pointers
  const f16* xrd0 = &xs[0][l16 * PADW + lhi * 8];
  const f16* xrd1 = &xs[1][l16 * PADW + lhi * 8];
  const f16* hrd0 = &hs[0][l16 * PADW + lhi * 8];
  const f16* hrd1 = &hs[1][l16 * PADW + lhi * 8];
  f16* hwr0 = &hs[0][l16 * PADW + c4];
  f16* hwr1 = &hs[1][l16 * PADW + c4];
  f16* xst0 = &xs[0][srow * PADW + cc * 4];
  f16* xst1 = &xs[1][srow * PADW + cc * 4];

  // running global pointers
  const float* pxA32 = xf32 ? (xf32 + ((size_t)(b0 + srow) * T) * H + cc * 4) : nullptr;
  const f16*   pxA16 = xf16 ? (xf16 + ((size_t)(b0 + srow) * T) * H + cc * 4) : nullptr;
  const float* attB  = AUG ? (att + (size_t)(b0 + l16) * T) : nullptr;
  f16*         histp = (!AUG && histo) ? (histo + ((size_t)(b0 + l16) * T) * H + c4) : nullptr;
  float*       outpp = AUG ? (outp + (size_t)(b0 + l16) * H + c4) : nullptr;

  // prologue: zero h buf 0, stage x_0, prefetch x_1 into Pa
  {
    f16x4 z4 = {(f16)0, (f16)0, (f16)0, (f16)0};
    *(f16x4*)(&hs[0][srow * PADW + cc * 4]) = z4;
    if (AUG) {
      f16x4 v = *(const f16x4*)(pxA16);
      *(f16x4*)xst0 = v;
    } else {
      f32x4 v = *(const f32x4*)(pxA32);
      f16x4 h4 = {(f16)v.x, (f16)v.y, (f16)v.z, (f16)v.w};
      *(f16x4*)xst0 = h4;
    }
  }
  f32x4 Pa32 = {0,0,0,0}, Pb32 = {0,0,0,0};
  f16x4 Pa16 = {(f16)0,(f16)0,(f16)0,(f16)0}, Pb16 = Pa16;
  float Aa = 0.f, Ab = 0.f;
  if (AUG) {
    Pa16 = *(const f16x4*)(pxA16 + H);
    Aa = attB[0];
    if (T > 1) Ab = attB[1];
  } else {
    Pa32 = *(const f32x4*)(pxA32 + H);
  }
  const float* pxE32 = pxA32 ? pxA32 + 2 * H : nullptr;
  const float* pxO32 = pxA32 ? pxA32 + 3 * H : nullptr;
  const f16*   pxE16 = pxA16 ? pxA16 + 2 * H : nullptr;
  const f16*   pxO16 = pxA16 ? pxA16 + 3 * H : nullptr;
  lds_sync();

#define STEP(targ_, XRD, HRD, HWRN, XSTN, PW32, PL32, PW16, PL16, AW, PXP32, PXP16) \
  {                                                                            \
    const int t5_  = (targ_);                                                  \
    float at_ = 0.f;                                                           \
    if (AUG) at_ = AW;                                                         \
    if (t5_ + 2 < T) {                                                         \
      if (AUG) {                                                               \
        PL16 = *(const f16x4*)(PXP16);  PXP16 += 2 * H;                        \
        AW = attB[t5_ + 2];                                                    \
      } else {                                                                 \
        PL32 = *(const f32x4*)(PXP32);  PXP32 += 2 * H;                        \
      }                                                                        \
    }                                                                          \
    f16x8 xb[4], hb[4];                                                        \
    _Pragma("unroll")                                                          \
    for (int q = 0; q < 4; ++q) {                                              \
      xb[q] = *(const f16x8*)(XRD + q * 32);                                   \
      hb[q] = *(const f16x8*)(HRD + q * 32);                                   \
    }                                                                          \
    f32x4 aR = bR, aZ = bZ, aXn = bXn, aHn = bHn;                              \
    _Pragma("unroll")                                                          \
    for (int q = 0; q < 4; ++q) {                                              \
      aR  = __builtin_amdgcn_mfma_f32_16x16x32_f16(wih[0][q], xb[q], aR, 0,0,0);  \
      aZ  = __builtin_amdgcn_mfma_f32_16x16x32_f16(wih[1][q], xb[q], aZ, 0,0,0);  \
      aXn = __builtin_amdgcn_mfma_f32_16x16x32_f16(wih[2][q], xb[q], aXn,0,0,0);  \
      aHn = __builtin_amdgcn_mfma_f32_16x16x32_f16(whh[2][q], hb[q], aHn,0,0,0);  \
    }                                                                          \
    _Pragma("unroll")                                                          \
    for (int q = 0; q < 4; ++q) {                                              \
      aR  = __builtin_amdgcn_mfma_f32_16x16x32_f16(whh[0][q], hb[q], aR, 0,0,0);  \
      aZ  = __builtin_amdgcn_mfma_f32_16x16x32_f16(whh[1][q], hb[q], aZ, 0,0,0);  \
    }                                                                          \
    float hn_[4];                                                              \
    _Pragma("unroll")                                                          \
    for (int i = 0; i < 4; ++i) {                                              \
      float r = sigmoidf_(aR[i]);                                              \
      float z = sigmoidf_(aZ[i]);                                              \
      float n = tanhf_(aXn[i] + r * aHn[i]);                                   \
      float h;                                                                 \
      if (AUG) { float u = z * at_; h = hold[i] + u * (n - hold[i]); }         \
      else     { h = n + z * (hold[i] - n); }                                  \
      hold[i] = h; hn_[i] = h;                                                 \
    }                                                                          \
    f16x4 hv = {(f16)hn_[0], (f16)hn_[1], (f16)hn_[2], (f16)hn_[3]};           \
    *(f16x4*)(HWRN) = hv;                                                      \
    if (!AUG) {                                                                \
      *(f16x4*)histp = hv;  histp += H;                                        \
    } else {                                                                   \
      if (t5_ == len_l - 1) {                                                  \
        f32x4 ov = {hn_[0], hn_[1], hn_[2], hn_[3]};                           \
        *(f32x4*)outpp = ov;                                                   \
      }                                                                        \
    }                                                                          \
    if (t5_ + 1 < T) {                                                         \
      if (AUG) {                                                               \
        *(f16x4*)(XSTN) = PW16;                                                \
      } else {                                                                 \
        f16x4 s4 = {(f16)PW32.x, (f16)PW32.y, (f16)PW32.z, (f16)PW32.w};       \
        *(f16x4*)(XSTN) = s4;                                                  \
      }                                                                        \
    }                                                                          \
    lds_sync();                                                                \
  }

  for (int t = 0; t < T; t += 2) {
    STEP(t,     xrd0, hrd0, hwr1, xst1, Pa32, Pb32, Pa16, Pb16, Aa, pxE32, pxE16)
    STEP(t + 1, xrd1, hrd1, hwr0, xst0, Pb32, Pa32, Pb16, Pa16, Ab, pxO32, pxO16)
  }
#undef STEP
}

// ---------------- DIN attention (MFMA version; rcp sigmoid) ----------------
__global__ __launch_bounds__(256)
void attn_kernel(const float* __restrict__ query,
                 const f16*   __restrict__ hist,
                 const int*   __restrict__ mask,
                 const float* __restrict__ W1, const float* __restrict__ b1,
                 const float* __restrict__ W2, const float* __restrict__ b2,
                 float* __restrict__ attv, int T)
{
  __shared__ float qs[H];
  __shared__ f16   WqH[48 * PADW];
  __shared__ float qcp[48], w2p[48];
  __shared__ float logitsS[224];
  __shared__ float red[256];

  const int tid = threadIdx.x, b = blockIdx.x;
  const int w = tid >> 6, l = tid & 63, l16 = l & 15, lhi = l >> 4;

  if (tid < H) qs[tid] = query[b * H + tid];
  if (tid < 48) w2p[tid] = (tid < AH) ? W2[tid] : 0.f;
  __syncthreads();

  for (int i = tid; i < 48 * H; i += 256) {
    int u = i >> 7, k = i & (H - 1);
    float v = 0.f;
    if (u < AH) {
      const float* r = W1 + u * 4 * H;
      v = r[H + k] - r[2*H + k] + qs[k] * r[3*H + k];
    }
    WqH[u * PADW + k] = (f16)v;
  }
  if (tid < 48) {
    float s = 0.f;
    if (tid < AH) {
      const float* r = W1 + tid * 4 * H;
      s = b1[tid];
      for (int k = 0; k < H; ++k) s += qs[k] * (r[k] + r[2*H + k]);
    }
    qcp[tid] = s;
  }
  __syncthreads();

  const f32x4 qcv0 = *(const f32x4*)&qcp[lhi*4];
  const f32x4 qcv1 = *(const f32x4*)&qcp[16 + lhi*4];
  const f32x4 qcv2 = *(const f32x4*)&qcp[32 + lhi*4];
  const f32x4 w2v0 = *(const f32x4*)&w2p[lhi*4];
  const f32x4 w2v1 = *(const f32x4*)&w2p[16 + lhi*4];
  const f32x4 w2v2 = *(const f32x4*)&w2p[32 + lhi*4];

  const int NMT = (T + 15) >> 4;
  for (int mt = w; mt < NMT; mt += 4) {
    const int t0 = mt * 16;
    f16x8 hbf[4];
    #pragma unroll
    for (int q = 0; q < 4; ++q)
      hbf[q] = *(const f16x8*)(hist + ((size_t)b*T + t0 + l16)*H + q*32 + lhi*8);
    f32x4 d0 = {0,0,0,0}, d1 = {0,0,0,0}, d2 = {0,0,0,0};
    #pragma unroll
    for (int q = 0; q < 4; ++q) {
      f16x8 wq0 = *(const f16x8*)(&WqH[ l16       * PADW + q*32 + lhi*8]);
      f16x8 wq1 = *(const f16x8*)(&WqH[(16 + l16) * PADW + q*32 + lhi*8]);
      f16x8 wq2 = *(const f16x8*)(&WqH[(32 + l16) * PADW + q*32 + lhi*8]);
      d0 = __builtin_amdgcn_mfma_f32_16x16x32_f16(wq0, hbf[q], d0, 0,0,0);
      d1 = __builtin_amdgcn_mfma_f32_16x16x32_f16(wq1, hbf[q], d1, 0,0,0);
      d2 = __builtin_amdgcn_mfma_f32_16x16x32_f16(wq2, hbf[q], d2, 0,0,0);
    }
    float p = 0.f;
    #pragma unroll
    for (int i = 0; i < 4; ++i) {
      p += w2v0[i] * sigmoidf_(d0[i] + qcv0[i]);
      p += w2v1[i] * sigmoidf_(d1[i] + qcv1[i]);
      p += w2v2[i] * sigmoidf_(d2[i] + qcv2[i]);
    }
    p += __shfl_xor(p, 16, 64);
    p += __shfl_xor(p, 32, 64);
    if (lhi == 0) logitsS[t0 + l16] = p;
  }
  __syncthreads();

  const int t = tid;
  float logit = -1e30f; int mk = 0;
  if (t < T) {
    mk = mask[(size_t)b*T + t];
    logit = (mk > 0) ? (logitsS[t] + b2[0]) : -1e30f;
  }
  red[tid] = logit; __syncthreads();
  for (int s = 128; s > 0; s >>= 1) { if (tid < s) red[tid] = fmaxf(red[tid], red[tid+s]); __syncthreads(); }
  float mx = red[0]; __syncthreads();
  float ev = (t < T && mk > 0) ? __expf(logit - mx) : 0.f;
  red[tid] = ev; __syncthreads();
  for (int s = 128; s > 0; s >>= 1) { if (tid < s) red[tid] += red[tid+s]; __syncthreads(); }
  float sm = red[0];
  if (t < T) attv[(size_t)b*T + t] = ev * __builtin_amdgcn_rcpf(sm);
}

// ---------------- host ----------------
extern "C" void kernel_launch(void* const* d_in, const int* in_sizes, int n_in,
                              void* d_out, int out_size, void* d_ws, size_t ws_size,
                              hipStream_t stream)
{
  const float* query = (const float*)d_in[0];
  const float* ub    = (const float*)d_in[1];
  const int*   mask  = (const int*)d_in[2];
  const float* gWih  = (const float*)d_in[3];
  const float* gWhh  = (const float*)d_in[4];
  const float* gbih  = (const float*)d_in[5];
  const float* gbhh  = (const float*)d_in[6];
  const float* aW1   = (const float*)d_in[7];
  const float* ab1   = (const float*)d_in[8];
  const float* aW2   = (const float*)d_in[9];
  const float* ab2   = (const float*)d_in[10];
  const float* uWih  = (const float*)d_in[11];
  const float* uWhh  = (const float*)d_in[12];
  const float* ubih  = (const float*)d_in[13];
  const float* ubhh  = (const float*)d_in[14];

  const int B = in_sizes[0] / H;            // 1024
  const int T = in_sizes[1] / in_sizes[0];  // 200

  // workspace layout
  char*  ws   = (char*)d_ws;
  f16*   wf   = (f16*)ws;                                   // 393216 B
  int*   lenp = (int*)(ws + 393216);                        // 4096 B
  float* attb = (float*)(ws + 397312);                      // B*T*4
  f16*   hist = (f16*)(ws + 397312 + (size_t)B * 200 * 4);  // B*T*H f16

  prep_weights<<<(4 * G3 * H + 255) / 256, 256, 0, stream>>>(gWih, gWhh, uWih, uWhh, wf);
  prep_len<<<(B + 255) / 256, 256, 0, stream>>>(mask, lenp, T, B);

  scan_kernel<false><<<B / 16, 512, 0, stream>>>(
      ub, (const f16*)nullptr, wf, wf + G3 * H, gbih, gbhh,
      (const float*)nullptr, (const int*)nullptr, hist, (float*)nullptr, T);

  attn_kernel<<<B, 256, 0, stream>>>(query, hist, mask, aW1, ab1, aW2, ab2, attb, T);

  scan_kernel<true><<<B / 16, 512, 0, stream>>>(
      (const float*)nullptr, hist, wf + 2 * G3 * H, wf + 3 * G3 * H, ubih, ubhh,
      attb, lenp, (f16*)nullptr, (float*)d_out, T);
}